// Round 9
// baseline (96.496 us; speedup 1.0000x reference)
//
#include <hip/hip_runtime.h>
#include <math.h>

#define CC   256               // threads per block
#define TILE 512               // elements per block (2 per thread)
#define SP   8                 // floats per LDS element slot (32B = 2x float4)
#define NY   (TILE + 33)       // y needed on [0, TILE+32]
#define NZ   (TILE + 25)       // k1 / z2 range
#define NK2  (TILE + 17)       // k2 / z3 range
#define NK3  (TILE + 9)        // k3 / z4 range
#define ISCL 0.0125f           // INTERACTION_SCALE / len(SHIFTS)

// ============================================================================
// Cl(3,0) ~= M2(C) via Pauli matrices:  e1->s1, e2->s2, e3->s3,
// e12 = i s3, e13 = -i s2, e23 = i s1, e123 = i I.
// Multivector a[8] (basis [1,e1,e2,e3,e12,e13,e23,e123]) <-> matrix
//   M = [[ (a0+a3)+i(a7+a4) , (a1-a5)+i(a6-a2) ],
//        [ (a1+a5)+i(a6+a2) , (a0-a3)+i(a7-a4) ]]
// stored as float m[8] = {M00r,M00i, M01r,M01i, M10r,M10i, M11r,M11i}.
// ============================================================================

// ---------------- complex primitives ----------------
__device__ __forceinline__ void cmul(float& orr, float& oi,
                                     float ar, float ai, float br, float bi) {
    orr = fmaf(ar, br, -(ai * bi));
    oi  = fmaf(ar, bi,   ai * br);
}
__device__ __forceinline__ void cmad(float& orr, float& oi,
                                     float ar, float ai, float br, float bi) {
    orr = fmaf(ar, br, fmaf(-ai, bi, orr));
    oi  = fmaf(ar, bi, fmaf( ai, br, oi));
}
__device__ __forceinline__ void cmsub(float& orr, float& oi,
                                      float ar, float ai, float br, float bi) {
    orr = fmaf(-ar, br, fmaf( ai, bi, orr));
    oi  = fmaf(-ar, bi, fmaf(-ai, br, oi));
}

// o = a * b  (2x2 complex matmul, 32 FMA)
__device__ __forceinline__ void mm2(const float* a, const float* b, float* o) {
    float r0,r1,r2,r3,r4,r5,r6,r7;
    cmul(r0,r1, a[0],a[1], b[0],b[1]); cmad(r0,r1, a[2],a[3], b[4],b[5]);
    cmul(r2,r3, a[0],a[1], b[2],b[3]); cmad(r2,r3, a[2],a[3], b[6],b[7]);
    cmul(r4,r5, a[4],a[5], b[0],b[1]); cmad(r4,r5, a[6],a[7], b[4],b[5]);
    cmul(r6,r7, a[4],a[5], b[2],b[3]); cmad(r6,r7, a[6],a[7], b[6],b[7]);
    o[0]=r0; o[1]=r1; o[2]=r2; o[3]=r3; o[4]=r4; o[5]=r5; o[6]=r6; o[7]=r7;
}

// ---------------- commutator (traceless operands) ----------------
// [A,W] with A traceless (u6 = {A00, A01, A10}); W given by off-diagonals
// W01, W10 and diagonal difference dW = W00 - W11. Result traceless:
//   C00 = A01*W10 - A10*W01 ; C01 = W01*dA - A01*dW ; C10 = A10*dW - W10*dA
// where dA = 2*A00.
__device__ __forceinline__ void comm_core2(const float* u6,
        float w01r, float w01i, float w10r, float w10i,
        float dwr, float dwi, float* o6) {
    const float dar = 2.f * u6[0], dai = 2.f * u6[1];
    float ar, ai;
    cmul (ar, ai, u6[2],u6[3], w10r,w10i);     // A01*W10
    cmsub(ar, ai, u6[4],u6[5], w01r,w01i);     // - A10*W01
    o6[0] = ar; o6[1] = ai;
    cmul (ar, ai, w01r,w01i, dar,dai);         // W01*dA
    cmsub(ar, ai, u6[2],u6[3], dwr,dwi);       // - A01*dW
    o6[2] = ar; o6[3] = ai;
    cmul (ar, ai, u6[4],u6[5], dwr,dwi);       // A10*dW
    cmsub(ar, ai, w10r,w10i, dar,dai);         // - W10*dA
    o6[4] = ar; o6[5] = ai;
}

// dexp^{-1}_{s*k}(w), order 4, Bernoulli (1,-1/2,1/6,0,-1/30).
// Cayley-Hamilton collapse: for traceless u in sl(2,C), ad_u^3 = 4*w_k*ad_u
// (exact; ad eigenvalues {0,0,+-2*delta}, w_k = delta^2 = u00^2 + u01*u10).
// Hence ad^4 = 4*w_k*ad^2 and the order-4 series is
//   res = w + c1*ad(w) + (c2 + 4*c4*w_k)*ad^2(w),  coefficient complex.
// Safe to call with o == k: k is only read to build u6 up front.
__device__ __forceinline__ void dexpinv8(const float* k, const float* w,
                                         float s, float* o) {
    float u6[6];
    u6[0] = 0.5f*(k[0]-k[6]); u6[1] = 0.5f*(k[1]-k[7]);
    u6[2] = k[2]; u6[3] = k[3]; u6[4] = k[4]; u6[5] = k[5];
    float a1[6], a2[6];
    comm_core2(u6, w[2],w[3], w[4],w[5], w[0]-w[6], w[1]-w[7], a1);   // ad^1
    comm_core2(u6, a1[2],a1[3], a1[4],a1[5], 2.f*a1[0], 2.f*a1[1], a2); // ad^2
    // w_k = u00^2 + u01*u10  (complex, unscaled k)
    float wkr = fmaf(u6[0],u6[0], -(u6[1]*u6[1]));
    wkr = fmaf(u6[2], u6[4], wkr); wkr = fmaf(-u6[3], u6[5], wkr);
    float wki = 2.f*u6[0]*u6[1];
    wki = fmaf(u6[2], u6[5], wki); wki = fmaf(u6[3], u6[4], wki);
    const float s2  = s*s;
    const float c1  = -0.5f*s;
    const float c2  = s2*(1.f/12.f);
    const float c4m = -(s2*s2)*(1.f/180.f);   // 4*c4 = -4 s^4/720
    const float gr = fmaf(c4m, wkr, c2), gi = c4m*wki;
    float acc[6];
#pragma unroll
    for (int p = 0; p < 3; ++p) {
        const float a2r = a2[2*p], a2i = a2[2*p+1];
        acc[2*p]   = fmaf(gr, a2r, fmaf(-gi, a2i, c1*a1[2*p]));
        acc[2*p+1] = fmaf(gr, a2i, fmaf( gi, a2r, c1*a1[2*p+1]));
    }
    o[0] = w[0] + acc[0]; o[1] = w[1] + acc[1];
    o[2] = w[2] + acc[2]; o[3] = w[3] + acc[3];
    o[4] = w[4] + acc[4]; o[5] = w[5] + acc[5];
    o[6] = w[6] - acc[0]; o[7] = w[7] - acc[1];
}

// ---------------- closed-form exp ----------------
// exp(s*k) = e^{c0} (cosh(d) I + sinhc(d) V), c0 = central part, V traceless,
// d^2 = w = V00^2 + V01*V10. cosh/sinhc as entire series in w.
// FAST (z-stages, |w| <~ 0.3, |c0| <~ 0.05): 3-term C/S series + 4-term
//   complex polynomial for e^{c0} (err ~ |c0|^4/24 ~ 3e-7) -- no TRANS ops.
// FULL (final exp, clipped u): 5-term series + __expf/__cosf/__sinf.
__device__ __forceinline__ void chstep(float& pr, float& pi,
                                       float wr, float wi, float K) {
    const float nr = fmaf(pr, wr, fmaf(-pi, wi, K));
    const float ni = fmaf(pr, wi, pi * wr);
    pr = nr; pi = ni;
}
template<bool FULL>
__device__ __forceinline__ void expm(const float* k, float s, float* o) {
    const float hs = 0.5f * s;
    const float c0r = hs*(k[0]+k[6]), c0i = hs*(k[1]+k[7]);
    const float v0r = hs*(k[0]-k[6]), v0i = hs*(k[1]-k[7]);
    const float v1r = s*k[2], v1i = s*k[3];
    const float v2r = s*k[4], v2i = s*k[5];
    float wr = fmaf(v0r, v0r, -(v0i*v0i));
    wr = fmaf(v1r, v2r, wr); wr = fmaf(-v1i, v2i, wr);
    float wi = 2.f*v0r*v0i;
    wi = fmaf(v1r, v2i, wi); wi = fmaf(v1i, v2r, wi);
    float Cr, Ci = 0.f, Sr, Si = 0.f;
    float er, ei;
    if (FULL) {
        Cr = 1.f/40320.f;                      // cosh: 1,1/2,1/24,1/720,1/40320
        chstep(Cr, Ci, wr, wi, 1.f/720.f);
        chstep(Cr, Ci, wr, wi, 1.f/24.f);
        chstep(Cr, Ci, wr, wi, 0.5f);
        chstep(Cr, Ci, wr, wi, 1.f);
        Sr = 1.f/362880.f;                     // sinhc: 1,1/6,1/120,1/5040,1/362880
        chstep(Sr, Si, wr, wi, 1.f/5040.f);
        chstep(Sr, Si, wr, wi, 1.f/120.f);
        chstep(Sr, Si, wr, wi, 1.f/6.f);
        chstep(Sr, Si, wr, wi, 1.f);
        const float ex = __expf(c0r);
        er = ex * __cosf(c0i);
        ei = ex * __sinf(c0i);
    } else {
        Cr = 1.f/24.f;                         // cosh: 1,1/2,1/24
        chstep(Cr, Ci, wr, wi, 0.5f);
        chstep(Cr, Ci, wr, wi, 1.f);
        Sr = 1.f/120.f;                        // sinhc: 1,1/6,1/120
        chstep(Sr, Si, wr, wi, 1.f/6.f);
        chstep(Sr, Si, wr, wi, 1.f);
        // e^{c0} = 1 + z(1 + z/2(1 + z/3)), z = c0  (Horner, complex)
        float t1r = fmaf(c0r, 1.f/3.f, 1.f), t1i = c0i * (1.f/3.f);
        float t2r, t2i;
        cmul(t2r, t2i, t1r, t1i, c0r, c0i);
        t2r = fmaf(0.5f, t2r, 1.f); t2i *= 0.5f;
        cmul(er, ei, t2r, t2i, c0r, c0i);
        er += 1.f;
    }
    float p0r, p0i; cmul(p0r, p0i, Sr, Si, v0r, v0i);     // S*V00
    const float tr = Cr + p0r, ti = Ci + p0i;
    const float ur = Cr - p0r, ui = Ci - p0i;
    cmul(o[0], o[1], er, ei, tr, ti);
    cmul(o[6], o[7], er, ei, ur, ui);
    float qr, qi; cmul(qr, qi, er, ei, Sr, Si);           // e^{c0}*S
    cmul(o[2], o[3], qr, qi, v1r, v1i);
    cmul(o[4], o[5], qr, qi, v2r, v2i);
}

// ---------------- LDS access (b128-vectorized, bank-swizzled) ----------------
__device__ __forceinline__ int sbase(int e) { return (e << 3) ^ (e & 4); }

__device__ __forceinline__ void lds_load8(const float* buf, int e, float* o) {
    const int b = sbase(e);
    float4 a = *(const float4*)(buf + b);
    float4 c = *(const float4*)(buf + (b ^ 4));
    o[0] = a.x; o[1] = a.y; o[2] = a.z; o[3] = a.w;
    o[4] = c.x; o[5] = c.y; o[6] = c.z; o[7] = c.w;
}
__device__ __forceinline__ void lds_store8(float* buf, int e, const float* v) {
    const int b = sbase(e);
    *(float4*)(buf + b)       = make_float4(v[0], v[1], v[2], v[3]);
    *(float4*)(buf + (b ^ 4)) = make_float4(v[4], v[5], v[6], v[7]);
}

// vector_field (matrix rep): derivative map + ISCL * z0 * bc
// bc accumulated rolling (peak live: z0 + bc + one t = 24 floats)
__device__ __forceinline__ void vf8_lds(const float* buf, int e, float* o) {
    float z0[8], bc[8], t[8], g[8];
    lds_load8(buf, e,     z0);
    lds_load8(buf, e + 1, bc);
    lds_load8(buf, e + 2, t);
#pragma unroll
    for (int c = 0; c < 8; ++c) bc[c] = fmaf(0.5f, t[c], bc[c]);
    lds_load8(buf, e + 4, t);
#pragma unroll
    for (int c = 0; c < 8; ++c) bc[c] = fmaf(0.25f, t[c], bc[c]);
    lds_load8(buf, e + 8, t);
#pragma unroll
    for (int c = 0; c < 8; ++c) bc[c] = fmaf(0.125f, t[c], bc[c]);
    mm2(z0, bc, g);
    const float Sr  = z0[2]+z0[4], Si  = z0[3]+z0[5];   // M01+M10
    const float Ddr = z0[0]-z0[6], Ddi = z0[1]-z0[7];   // M00-M11
    const float Tr  = z0[4]-z0[2], Ti  = z0[5]-z0[3];   // M10-M01
    o[0] = fmaf(ISCL, g[0],  0.5f*Si);
    o[1] = fmaf(ISCL, g[1], -0.5f*Sr);
    o[2] = fmaf(ISCL, g[2],  0.5f*(Ddi+Ti));
    o[3] = fmaf(ISCL, g[3], -0.5f*(Ddr+Tr));
    o[4] = fmaf(ISCL, g[4],  0.5f*(Ddi-Ti));
    o[5] = fmaf(ISCL, g[5], -0.5f*(Ddr-Tr));
    o[6] = fmaf(ISCL, g[6], -0.5f*Si);
    o[7] = fmaf(ISCL, g[7],  0.5f*Sr);
}

// z = exp(scale*k) * y[e] -> zbuf[e]  (fast exp: z-stage scales only)
__device__ __forceinline__ void zstage(const float* ybuf, float* zbuf, int e,
                                       const float* k, float scale) {
    float ex[8], yv[8], o[8];
    expm<false>(k, scale, ex);
    lds_load8(ybuf, e, yv);
    mm2(ex, yv, o);
    lds_store8(zbuf, e, o);
}

// kout = dexpinv(scale*kin, vf(z[e]))  -- kout == kin allowed
__device__ __forceinline__ void kstage(const float* zbuf, int e,
                                       const float* kin, float scale, float* kout) {
    float w[8];
    vf8_lds(zbuf, e, w);
    dexpinv8(kin, w, scale, kout);
}

__global__ __launch_bounds__(CC, 2)
void clifford_step_kernel(const float* __restrict__ y, float* __restrict__ out) {
    __shared__ __align__(16) float sy [NY  * SP];   // 17440 B (matrix rep)
    __shared__ __align__(16) float szA[NZ  * SP];   // 17184 B (z2, z4)
    __shared__ __align__(16) float szB[NK2 * SP];   // 16928 B (z3)

    const int tid   = threadIdx.x;
    const int row   = blockIdx.x >> 7;      // 65536/512 = 128 chunks per row
    const int chunk = blockIdx.x & 127;
    const int base  = chunk * TILE;
    // rotate the halo-heavy wave per block so heavy waves spread across SIMDs
    const int bt    = (tid - ((blockIdx.x & 3) << 6)) & 255;
    const float* __restrict__ yrow = y + (size_t)row * 65536u * 8u;

    // ---- load y tile (+halo 32) into LDS, converting mv -> matrix ----
    {
        auto loadY = [&](int e) {
            const int g = (base + e) & 65535;
            const float4* p = (const float4*)(yrow + (size_t)g * 8u);
            float4 A = p[0], B = p[1];     // a0..a3 | a4..a7
            const int s = sbase(e);
            *(float4*)&sy[s]     = make_float4(A.x + A.w, B.w + B.x, A.y - B.y, B.z - A.z);
            *(float4*)&sy[s ^ 4] = make_float4(A.y + B.y, B.z + A.z, A.x - A.w, B.w - B.x);
        };
        loadY(tid);
        loadY(tid + CC);
        if (bt < NY - TILE) loadY(TILE + bt);
    }
    __syncthreads();                         // bar0

    // ---- per-thread state: two main streams (e0 = tid, e1 = tid+256)
    //      + halo stream kb (threads with bt < range only) ----
    float ka0[8], ka1[8], kb[8], u0[8], u1[8];

    // ---- stage 1: k1 = vf(y); z2 = exp(0.05*k1)*y -> szA ----
    vf8_lds(sy, tid, ka0);
    vf8_lds(sy, tid + CC, ka1);
#pragma unroll
    for (int c = 0; c < 8; ++c) { u0[c] = ka0[c]; u1[c] = ka1[c]; }
    if (bt < NZ - TILE) vf8_lds(sy, TILE + bt, kb);
    zstage(sy, szA, tid,      ka0, 0.05f);
    zstage(sy, szA, tid + CC, ka1, 0.05f);
    if (bt < NZ - TILE) zstage(sy, szA, TILE + bt, kb, 0.05f);
    __syncthreads();                         // bar1: RAW on szA

    // ---- stage 2: k2 = dexpinv(0.05*k1, vf(z2)); z3 = exp(0.05*k2)*y -> szB ----
    kstage(szA, tid,      ka0, 0.05f, ka0);
    kstage(szA, tid + CC, ka1, 0.05f, ka1);
#pragma unroll
    for (int c = 0; c < 8; ++c) {
        u0[c] = fmaf(2.f, ka0[c], u0[c]);
        u1[c] = fmaf(2.f, ka1[c], u1[c]);
    }
    if (bt < NK2 - TILE) kstage(szA, TILE + bt, kb, 0.05f, kb);
    zstage(sy, szB, tid,      ka0, 0.05f);
    zstage(sy, szB, tid + CC, ka1, 0.05f);
    if (bt < NK2 - TILE) zstage(sy, szB, TILE + bt, kb, 0.05f);
    __syncthreads();                         // bar2: RAW on szB (+ szA reads done)

    // ---- stage 3: k3 = dexpinv(0.05*k2, vf(z3)); z4 = exp(0.1*k3)*y -> szA ----
    kstage(szB, tid,      ka0, 0.05f, ka0);
    kstage(szB, tid + CC, ka1, 0.05f, ka1);
#pragma unroll
    for (int c = 0; c < 8; ++c) {
        u0[c] = fmaf(2.f, ka0[c], u0[c]);
        u1[c] = fmaf(2.f, ka1[c], u1[c]);
    }
    if (bt < NK3 - TILE) kstage(szB, TILE + bt, kb, 0.05f, kb);
    zstage(sy, szA, tid,      ka0, 0.1f);
    zstage(sy, szA, tid + CC, ka1, 0.1f);
    if (bt < NK3 - TILE) zstage(sy, szA, TILE + bt, kb, 0.1f);
    __syncthreads();                         // bar3: RAW on szA

    // ---- tail: k4, u (sanitized in mv basis), output -- both streams ----
    {
        auto tail = [&](int e, const float* k3v, const float* uaccv) {
            float w[8], k4[8], um[8], ex[8], yv[8], om[8];
            vf8_lds(szA, e, w);
            dexpinv8(k3v, w, 0.1f, k4);

            const float s6 = 0.1f / 6.0f;
#pragma unroll
            for (int c = 0; c < 8; ++c)
                um[c] = s6 * (uaccv[c] + k4[c]);
            // matrix -> multivector coeffs, nan_to_num + clip, -> matrix
            float av[8];
            av[0] = 0.5f*(um[0]+um[6]); av[3] = 0.5f*(um[0]-um[6]);
            av[7] = 0.5f*(um[1]+um[7]); av[4] = 0.5f*(um[1]-um[7]);
            av[1] = 0.5f*(um[2]+um[4]); av[5] = 0.5f*(um[4]-um[2]);
            av[6] = 0.5f*(um[3]+um[5]); av[2] = 0.5f*(um[5]-um[3]);
#pragma unroll
            for (int c = 0; c < 8; ++c) {
                float v = av[c];
                if (isnan(v)) v = 0.f;       // nan_to_num(nan=0); clip handles +-inf
                av[c] = fmaxf(-1.f, fminf(v, 1.f));
            }
            um[0] = av[0]+av[3]; um[1] = av[7]+av[4];
            um[2] = av[1]-av[5]; um[3] = av[6]-av[2];
            um[4] = av[1]+av[5]; um[5] = av[6]+av[2];
            um[6] = av[0]-av[3]; um[7] = av[7]-av[4];

            expm<true>(um, 1.f, ex);
            lds_load8(sy, e, yv);
            mm2(ex, yv, om);

            float* dst = out + ((size_t)row * 65536u + (size_t)(base + e)) * 8u;
            ((float4*)dst)[0] = make_float4(0.5f*(om[0]+om[6]), 0.5f*(om[2]+om[4]),
                                            0.5f*(om[5]-om[3]), 0.5f*(om[0]-om[6]));
            ((float4*)dst)[1] = make_float4(0.5f*(om[1]-om[7]), 0.5f*(om[4]-om[2]),
                                            0.5f*(om[3]+om[5]), 0.5f*(om[1]+om[7]));
        };
        tail(tid,      ka0, u0);
        tail(tid + CC, ka1, u1);
    }
}

extern "C" void kernel_launch(void* const* d_in, const int* in_sizes, int n_in,
                              void* d_out, int out_size, void* d_ws, size_t ws_size,
                              hipStream_t stream) {
    const float* y = (const float*)d_in[0];
    float* out = (float*)d_out;
    dim3 grid(32 * 128);   // 32 rows x 128 chunks of 512 elements
    dim3 block(CC);
    hipLaunchKernelGGL(clifford_step_kernel, grid, block, 0, stream, y, out);
}

// Round 10
// 93.783 us; speedup vs baseline: 1.0289x; 1.0289x over previous
//
#include <hip/hip_runtime.h>
#include <math.h>

#define CC   256
#define SP   8                 // floats per LDS element slot (32B = 2x float4)
#define NY   (CC + 33)         // y needed on [0, C+32]
#define NZ   (CC + 25)         // k1 / z2 range
#define NK2  (CC + 17)         // k2 / z3 range
#define NK3  (CC + 9)          // k3 / z4 range
#define ISCL 0.0125f           // INTERACTION_SCALE / len(SHIFTS)

// ============================================================================
// Cl(3,0) ~= M2(C) via Pauli matrices (see round-4 header for the map).
// m[8] = {M00r,M00i, M01r,M01i, M10r,M10i, M11r,M11i}.
// ============================================================================

// ---------------- complex primitives ----------------
__device__ __forceinline__ void cmul(float& orr, float& oi,
                                     float ar, float ai, float br, float bi) {
    orr = fmaf(ar, br, -(ai * bi));
    oi  = fmaf(ar, bi,   ai * br);
}
__device__ __forceinline__ void cmad(float& orr, float& oi,
                                     float ar, float ai, float br, float bi) {
    orr = fmaf(ar, br, fmaf(-ai, bi, orr));
    oi  = fmaf(ar, bi, fmaf( ai, br, oi));
}
__device__ __forceinline__ void cmsub(float& orr, float& oi,
                                      float ar, float ai, float br, float bi) {
    orr = fmaf(-ar, br, fmaf( ai, bi, orr));
    oi  = fmaf(-ar, bi, fmaf(-ai, br, oi));
}

// o = a * b  (2x2 complex matmul, 32 FMA)
__device__ __forceinline__ void mm2(const float* a, const float* b, float* o) {
    float r0,r1,r2,r3,r4,r5,r6,r7;
    cmul(r0,r1, a[0],a[1], b[0],b[1]); cmad(r0,r1, a[2],a[3], b[4],b[5]);
    cmul(r2,r3, a[0],a[1], b[2],b[3]); cmad(r2,r3, a[2],a[3], b[6],b[7]);
    cmul(r4,r5, a[4],a[5], b[0],b[1]); cmad(r4,r5, a[6],a[7], b[4],b[5]);
    cmul(r6,r7, a[4],a[5], b[2],b[3]); cmad(r6,r7, a[6],a[7], b[6],b[7]);
    o[0]=r0; o[1]=r1; o[2]=r2; o[3]=r3; o[4]=r4; o[5]=r5; o[6]=r6; o[7]=r7;
}

// ---------------- commutator (traceless operands) ----------------
__device__ __forceinline__ void comm_core2(const float* u6,
        float w01r, float w01i, float w10r, float w10i,
        float dwr, float dwi, float* o6) {
    const float dar = 2.f * u6[0], dai = 2.f * u6[1];
    float ar, ai;
    cmul (ar, ai, u6[2],u6[3], w10r,w10i);     // A01*W10
    cmsub(ar, ai, u6[4],u6[5], w01r,w01i);     // - A10*W01
    o6[0] = ar; o6[1] = ai;
    cmul (ar, ai, w01r,w01i, dar,dai);         // W01*dA
    cmsub(ar, ai, u6[2],u6[3], dwr,dwi);       // - A01*dW
    o6[2] = ar; o6[3] = ai;
    cmul (ar, ai, u6[4],u6[5], dwr,dwi);       // A10*dW
    cmsub(ar, ai, w10r,w10i, dar,dai);         // - W10*dA
    o6[4] = ar; o6[5] = ai;
}

// dexp^{-1}_{s*k}(w), order 4, Cayley-Hamilton-collapsed (exact):
//   res = w + c1*ad(w) + (c2 + 4*c4*w_k)*ad^2(w).  Safe with o == k.
__device__ __forceinline__ void dexpinv8(const float* k, const float* w,
                                         float s, float* o) {
    float u6[6];
    u6[0] = 0.5f*(k[0]-k[6]); u6[1] = 0.5f*(k[1]-k[7]);
    u6[2] = k[2]; u6[3] = k[3]; u6[4] = k[4]; u6[5] = k[5];
    float a1[6], a2[6];
    comm_core2(u6, w[2],w[3], w[4],w[5], w[0]-w[6], w[1]-w[7], a1);     // ad^1
    comm_core2(u6, a1[2],a1[3], a1[4],a1[5], 2.f*a1[0], 2.f*a1[1], a2); // ad^2
    float wkr = fmaf(u6[0],u6[0], -(u6[1]*u6[1]));
    wkr = fmaf(u6[2], u6[4], wkr); wkr = fmaf(-u6[3], u6[5], wkr);
    float wki = 2.f*u6[0]*u6[1];
    wki = fmaf(u6[2], u6[5], wki); wki = fmaf(u6[3], u6[4], wki);
    const float s2  = s*s;
    const float c1  = -0.5f*s;
    const float c2  = s2*(1.f/12.f);
    const float c4m = -(s2*s2)*(1.f/180.f);   // 4*c4
    const float gr = fmaf(c4m, wkr, c2), gi = c4m*wki;
    float acc[6];
#pragma unroll
    for (int p = 0; p < 3; ++p) {
        const float a2r = a2[2*p], a2i = a2[2*p+1];
        acc[2*p]   = fmaf(gr, a2r, fmaf(-gi, a2i, c1*a1[2*p]));
        acc[2*p+1] = fmaf(gr, a2i, fmaf( gi, a2r, c1*a1[2*p+1]));
    }
    o[0] = w[0] + acc[0]; o[1] = w[1] + acc[1];
    o[2] = w[2] + acc[2]; o[3] = w[3] + acc[3];
    o[4] = w[4] + acc[4]; o[5] = w[5] + acc[5];
    o[6] = w[6] - acc[0]; o[7] = w[7] - acc[1];
}

// ---------------- closed-form exp ----------------
__device__ __forceinline__ void chstep(float& pr, float& pi,
                                       float wr, float wi, float K) {
    const float nr = fmaf(pr, wr, fmaf(-pi, wi, K));
    const float ni = fmaf(pr, wi, pi * wr);
    pr = nr; pi = ni;
}
template<bool FULL>
__device__ __forceinline__ void expm(const float* k, float s, float* o) {
    const float hs = 0.5f * s;
    const float c0r = hs*(k[0]+k[6]), c0i = hs*(k[1]+k[7]);
    const float v0r = hs*(k[0]-k[6]), v0i = hs*(k[1]-k[7]);
    const float v1r = s*k[2], v1i = s*k[3];
    const float v2r = s*k[4], v2i = s*k[5];
    float wr = fmaf(v0r, v0r, -(v0i*v0i));
    wr = fmaf(v1r, v2r, wr); wr = fmaf(-v1i, v2i, wr);
    float wi = 2.f*v0r*v0i;
    wi = fmaf(v1r, v2i, wi); wi = fmaf(v1i, v2r, wi);
    float Cr, Ci = 0.f, Sr, Si = 0.f;
    float er, ei;
    if (FULL) {
        Cr = 1.f/40320.f;
        chstep(Cr, Ci, wr, wi, 1.f/720.f);
        chstep(Cr, Ci, wr, wi, 1.f/24.f);
        chstep(Cr, Ci, wr, wi, 0.5f);
        chstep(Cr, Ci, wr, wi, 1.f);
        Sr = 1.f/362880.f;
        chstep(Sr, Si, wr, wi, 1.f/5040.f);
        chstep(Sr, Si, wr, wi, 1.f/120.f);
        chstep(Sr, Si, wr, wi, 1.f/6.f);
        chstep(Sr, Si, wr, wi, 1.f);
        const float ex = __expf(c0r);
        er = ex * __cosf(c0i);
        ei = ex * __sinf(c0i);
    } else {
        Cr = 1.f/24.f;
        chstep(Cr, Ci, wr, wi, 0.5f);
        chstep(Cr, Ci, wr, wi, 1.f);
        Sr = 1.f/120.f;
        chstep(Sr, Si, wr, wi, 1.f/6.f);
        chstep(Sr, Si, wr, wi, 1.f);
        float t1r = fmaf(c0r, 1.f/3.f, 1.f), t1i = c0i * (1.f/3.f);
        float t2r, t2i;
        cmul(t2r, t2i, t1r, t1i, c0r, c0i);
        t2r = fmaf(0.5f, t2r, 1.f); t2i *= 0.5f;
        cmul(er, ei, t2r, t2i, c0r, c0i);
        er += 1.f;
    }
    float p0r, p0i; cmul(p0r, p0i, Sr, Si, v0r, v0i);
    const float tr = Cr + p0r, ti = Ci + p0i;
    const float ur = Cr - p0r, ui = Ci - p0i;
    cmul(o[0], o[1], er, ei, tr, ti);
    cmul(o[6], o[7], er, ei, ur, ui);
    float qr, qi; cmul(qr, qi, er, ei, Sr, Si);
    cmul(o[2], o[3], qr, qi, v1r, v1i);
    cmul(o[4], o[5], qr, qi, v2r, v2i);
}

// ---------------- LDS access (b128-vectorized, bank-swizzled) ----------------
__device__ __forceinline__ int sbase(int e) { return (e << 3) ^ (e & 4); }

__device__ __forceinline__ void lds_load8(const float* buf, int e, float* o) {
    const int b = sbase(e);
    float4 a = *(const float4*)(buf + b);
    float4 c = *(const float4*)(buf + (b ^ 4));
    o[0] = a.x; o[1] = a.y; o[2] = a.z; o[3] = a.w;
    o[4] = c.x; o[5] = c.y; o[6] = c.z; o[7] = c.w;
}
__device__ __forceinline__ void lds_store8(float* buf, int e, const float* v) {
    const int b = sbase(e);
    *(float4*)(buf + b)       = make_float4(v[0], v[1], v[2], v[3]);
    *(float4*)(buf + (b ^ 4)) = make_float4(v[4], v[5], v[6], v[7]);
}

// ---- vector_field core given own z0 (registers) + neighbor buffer ----
__device__ __forceinline__ void vf8_core(const float* buf, int e,
                                         const float* z0, float* o) {
    float bc[8], t[8], g[8];
    lds_load8(buf, e + 1, bc);
    lds_load8(buf, e + 2, t);
#pragma unroll
    for (int c = 0; c < 8; ++c) bc[c] = fmaf(0.5f, t[c], bc[c]);
    lds_load8(buf, e + 4, t);
#pragma unroll
    for (int c = 0; c < 8; ++c) bc[c] = fmaf(0.25f, t[c], bc[c]);
    lds_load8(buf, e + 8, t);
#pragma unroll
    for (int c = 0; c < 8; ++c) bc[c] = fmaf(0.125f, t[c], bc[c]);
    mm2(z0, bc, g);
    const float Sr  = z0[2]+z0[4], Si  = z0[3]+z0[5];   // M01+M10
    const float Ddr = z0[0]-z0[6], Ddi = z0[1]-z0[7];   // M00-M11
    const float Tr  = z0[4]-z0[2], Ti  = z0[5]-z0[3];   // M10-M01
    o[0] = fmaf(ISCL, g[0],  0.5f*Si);
    o[1] = fmaf(ISCL, g[1], -0.5f*Sr);
    o[2] = fmaf(ISCL, g[2],  0.5f*(Ddi+Ti));
    o[3] = fmaf(ISCL, g[3], -0.5f*(Ddr+Tr));
    o[4] = fmaf(ISCL, g[4],  0.5f*(Ddi-Ti));
    o[5] = fmaf(ISCL, g[5], -0.5f*(Ddr-Tr));
    o[6] = fmaf(ISCL, g[6], -0.5f*Si);
    o[7] = fmaf(ISCL, g[7],  0.5f*Sr);
}

// halo path: own z0 also from LDS
__device__ __forceinline__ void vf8_lds(const float* buf, int e, float* o) {
    float z0[8];
    lds_load8(buf, e, z0);
    vf8_core(buf, e, z0, o);
}

// main stream: z = exp(scale*k)*y(reg); store to LDS AND keep in reg
__device__ __forceinline__ void zstage_own(float* zbuf, int e, const float* k,
                                           float scale, const float* yv, float* zreg) {
    float ex[8];
    expm<false>(k, scale, ex);
    mm2(ex, yv, zreg);
    lds_store8(zbuf, e, zreg);
}

// halo stream: y from LDS, z to LDS only
__device__ __forceinline__ void zstage(const float* ybuf, float* zbuf, int e,
                                       const float* k, float scale) {
    float ex[8], yv[8], o[8];
    expm<false>(k, scale, ex);
    lds_load8(ybuf, e, yv);
    mm2(ex, yv, o);
    lds_store8(zbuf, e, o);
}

// halo: kout = dexpinv(scale*kin, vf(z[e]))  -- kout == kin allowed
__device__ __forceinline__ void kstage(const float* zbuf, int e,
                                       const float* kin, float scale, float* kout) {
    float w[8];
    vf8_lds(zbuf, e, w);
    dexpinv8(kin, w, scale, kout);
}

__global__ __launch_bounds__(CC, 3)
void clifford_step_kernel(const float* __restrict__ y, float* __restrict__ out) {
    __shared__ __align__(16) float sy [NY  * SP];  // 9248 B (matrix rep)
    __shared__ __align__(16) float szA[NZ  * SP];  // 8992 B (z2, z4)
    __shared__ __align__(16) float szB[NK2 * SP];  // 8736 B (z3)

    const int tid   = threadIdx.x;
    const int row   = blockIdx.x >> 8;      // 65536/256 = 256 chunks per row
    const int chunk = blockIdx.x & 255;
    const int base  = chunk * CC;
    // rotate the halo-heavy wave per block so heavy waves spread across SIMDs
    const int bt    = (tid - ((blockIdx.x & 3) << 6)) & 255;
    const float* __restrict__ yrow = y + (size_t)row * 65536u * 8u;

    // ---- load y tile (+halo 32) into LDS (matrix rep); own y kept in regs ----
    float yreg[8];
    {
        const int g0 = (base + tid) & 65535;
        const float4* p = (const float4*)(yrow + (size_t)g0 * 8u);
        float4 A = p[0], B = p[1];     // a0..a3 | a4..a7
        yreg[0] = A.x + A.w; yreg[1] = B.w + B.x;
        yreg[2] = A.y - B.y; yreg[3] = B.z - A.z;
        yreg[4] = A.y + B.y; yreg[5] = B.z + A.z;
        yreg[6] = A.x - A.w; yreg[7] = B.w - B.x;
        lds_store8(sy, tid, yreg);
        if (bt < NY - CC) {
            const int e  = CC + bt;
            const int g1 = (base + e) & 65535;
            const float4* q = (const float4*)(yrow + (size_t)g1 * 8u);
            float4 Cv = q[0], D = q[1];
            const int s2 = sbase(e);
            *(float4*)&sy[s2]     = make_float4(Cv.x + Cv.w, D.w + D.x, Cv.y - D.y, D.z - Cv.z);
            *(float4*)&sy[s2 ^ 4] = make_float4(Cv.y + D.y, D.z + Cv.z, Cv.x - Cv.w, D.w - D.x);
        }
    }
    __syncthreads();                         // bar0

    // ---- per-thread state: ka (current k), uacc, zreg (own z), yreg;
    //      halo stream kb on heavy threads only ----
    float ka[8], uacc[8], zreg[8], kb[8];

    // ---- stage 1: k1 = vf(y); z2 = exp(0.05*k1)*y -> szA ----
    vf8_core(sy, tid, yreg, ka);
#pragma unroll
    for (int c = 0; c < 8; ++c) uacc[c] = ka[c];
    zstage_own(szA, tid, ka, 0.05f, yreg, zreg);
    if (bt < NZ - CC) {
        vf8_lds(sy, CC + bt, kb);
        zstage(sy, szA, CC + bt, kb, 0.05f);
    }
    __syncthreads();                         // bar1: RAW on szA

    // ---- stage 2: k2 = dexpinv(0.05*k1, vf(z2)); z3 = exp(0.05*k2)*y -> szB ----
    {
        float w[8];
        vf8_core(szA, tid, zreg, w);
        dexpinv8(ka, w, 0.05f, ka);
    }
#pragma unroll
    for (int c = 0; c < 8; ++c) uacc[c] = fmaf(2.f, ka[c], uacc[c]);
    zstage_own(szB, tid, ka, 0.05f, yreg, zreg);
    if (bt < NK2 - CC) {
        kstage(szA, CC + bt, kb, 0.05f, kb);
        zstage(sy, szB, CC + bt, kb, 0.05f);
    }
    __syncthreads();                         // bar2: RAW on szB (+ szA reads done)

    // ---- stage 3: k3 = dexpinv(0.05*k2, vf(z3)); z4 = exp(0.1*k3)*y -> szA ----
    {
        float w[8];
        vf8_core(szB, tid, zreg, w);
        dexpinv8(ka, w, 0.05f, ka);
    }
#pragma unroll
    for (int c = 0; c < 8; ++c) uacc[c] = fmaf(2.f, ka[c], uacc[c]);
    zstage_own(szA, tid, ka, 0.1f, yreg, zreg);
    if (bt < NK3 - CC) {
        kstage(szB, CC + bt, kb, 0.05f, kb);
        zstage(sy, szA, CC + bt, kb, 0.1f);
    }
    __syncthreads();                         // bar3: RAW on szA

    // ---- tail: k4, u (sanitized in mv basis), output ----
    {
        float w[8], k4[8], um[8], ex[8], om[8];
        vf8_core(szA, tid, zreg, w);
        dexpinv8(ka, w, 0.1f, k4);           // ka == k3

        const float s6 = 0.1f / 6.0f;
#pragma unroll
        for (int c = 0; c < 8; ++c)
            um[c] = s6 * (uacc[c] + k4[c]);
        // matrix -> multivector coeffs, nan_to_num + clip, -> matrix
        float av[8];
        av[0] = 0.5f*(um[0]+um[6]); av[3] = 0.5f*(um[0]-um[6]);
        av[7] = 0.5f*(um[1]+um[7]); av[4] = 0.5f*(um[1]-um[7]);
        av[1] = 0.5f*(um[2]+um[4]); av[5] = 0.5f*(um[4]-um[2]);
        av[6] = 0.5f*(um[3]+um[5]); av[2] = 0.5f*(um[5]-um[3]);
#pragma unroll
        for (int c = 0; c < 8; ++c) {
            float v = av[c];
            if (isnan(v)) v = 0.f;           // nan_to_num(nan=0); clip handles +-inf
            av[c] = fmaxf(-1.f, fminf(v, 1.f));
        }
        um[0] = av[0]+av[3]; um[1] = av[7]+av[4];
        um[2] = av[1]-av[5]; um[3] = av[6]-av[2];
        um[4] = av[1]+av[5]; um[5] = av[6]+av[2];
        um[6] = av[0]-av[3]; um[7] = av[7]-av[4];

        expm<true>(um, 1.f, ex);
        mm2(ex, yreg, om);

        float* dst = out + ((size_t)row * 65536u + (size_t)(base + tid)) * 8u;
        ((float4*)dst)[0] = make_float4(0.5f*(om[0]+om[6]), 0.5f*(om[2]+om[4]),
                                        0.5f*(om[5]-om[3]), 0.5f*(om[0]-om[6]));
        ((float4*)dst)[1] = make_float4(0.5f*(om[1]-om[7]), 0.5f*(om[4]-om[2]),
                                        0.5f*(om[3]+om[5]), 0.5f*(om[1]+om[7]));
    }
}

extern "C" void kernel_launch(void* const* d_in, const int* in_sizes, int n_in,
                              void* d_out, int out_size, void* d_ws, size_t ws_size,
                              hipStream_t stream) {
    const float* y = (const float*)d_in[0];
    float* out = (float*)d_out;
    dim3 grid(32 * 256);   // 32 rows x 256 chunks of 256 elements
    dim3 block(CC);
    hipLaunchKernelGGL(clifford_step_kernel, grid, block, 0, stream, y, out);
}

// Round 11
// 77.881 us; speedup vs baseline: 1.2390x; 1.2042x over previous
//
#include <hip/hip_runtime.h>
#include <math.h>

#define CC   256
#define SP   8                 // floats per LDS element slot (32B = 2x float4)
#define NY   (CC + 33)         // y needed on [0, C+32]
#define NZ   (CC + 25)         // k1 / z2 range
#define NK2  (CC + 17)         // k2 / z3 range
#define NK3  (CC + 9)          // k3 / z4 range
#define ISCL 0.0125f           // INTERACTION_SCALE / len(SHIFTS)

// ============================================================================
// Cl(3,0) ~= M2(C) via Pauli matrices. Matrix stored as REAL/IMAG PLANES so
// (re,im)-independent FMA chains pair into v_pk_fma_f32 (packed FP32, 2/instr):
//   slot float[8] = { r00,r01, r10,r11, i00,i01, i10,i11 }
//   M2 = { r0=(r00,r01), r1=(r10,r11), i0=(i00,i01), i1=(i10,i11) }  (f32x2)
// mv a[8] <-> matrix:  M00=(a0+a3)+i(a7+a4), M01=(a1-a5)+i(a6-a2),
//                      M10=(a1+a5)+i(a6+a2), M11=(a0-a3)+i(a7-a4).
// ============================================================================

typedef float f32x2 __attribute__((ext_vector_type(2)));

__device__ __forceinline__ f32x2 mk2(float a, float b) { f32x2 v; v.x = a; v.y = b; return v; }
__device__ __forceinline__ f32x2 sp(float s)           { f32x2 v; v.x = s; v.y = s; return v; }
__device__ __forceinline__ f32x2 fma2(f32x2 a, f32x2 b, f32x2 c) {
    return __builtin_elementwise_fma(a, b, c);
}

struct M2 { f32x2 r0, r1, i0, i1; };

// ---------------- scalar complex helpers (for non-pairable parts) ----------
__device__ __forceinline__ void cmul(float& orr, float& oi,
                                     float ar, float ai, float br, float bi) {
    orr = fmaf(ar, br, -(ai * bi));
    oi  = fmaf(ar, bi,   ai * br);
}
__device__ __forceinline__ void cmsub(float& orr, float& oi,
                                      float ar, float ai, float br, float bi) {
    orr = fmaf(-ar, br, fmaf( ai, bi, orr));
    oi  = fmaf(-ar, bi, fmaf(-ai, br, oi));
}

// ---------------- packed 2x2 complex matmul: 16 pk-FMA --------------------
__device__ __forceinline__ M2 mm2p(const M2& a, const M2& b) {
    M2 o;
    o.r0 = fma2(sp(a.r0.x), b.r0, fma2(sp(a.r0.y), b.r1,
           fma2(sp(-a.i0.x), b.i0, sp(-a.i0.y) * b.i1)));
    o.i0 = fma2(sp(a.r0.x), b.i0, fma2(sp(a.r0.y), b.i1,
           fma2(sp(a.i0.x), b.r0, sp(a.i0.y) * b.r1)));
    o.r1 = fma2(sp(a.r1.x), b.r0, fma2(sp(a.r1.y), b.r1,
           fma2(sp(-a.i1.x), b.i0, sp(-a.i1.y) * b.i1)));
    o.i1 = fma2(sp(a.r1.x), b.i0, fma2(sp(a.r1.y), b.i1,
           fma2(sp(a.i1.x), b.r0, sp(a.i1.y) * b.r1)));
    return o;
}

// ---------------- commutator core (scalar complex; traceless operands) -----
// [A,W], A traceless (u6={A00,A01,A10}); W via W01,W10,dW=W00-W11; dA=2*A00.
__device__ __forceinline__ void comm_core2(const float* u6,
        float w01r, float w01i, float w10r, float w10i,
        float dwr, float dwi, float* o6) {
    const float dar = 2.f * u6[0], dai = 2.f * u6[1];
    float ar, ai;
    cmul (ar, ai, u6[2],u6[3], w10r,w10i);     // A01*W10
    cmsub(ar, ai, u6[4],u6[5], w01r,w01i);     // - A10*W01
    o6[0] = ar; o6[1] = ai;
    cmul (ar, ai, w01r,w01i, dar,dai);         // W01*dA
    cmsub(ar, ai, u6[2],u6[3], dwr,dwi);       // - A01*dW
    o6[2] = ar; o6[3] = ai;
    cmul (ar, ai, u6[4],u6[5], dwr,dwi);       // A10*dW
    cmsub(ar, ai, w10r,w10i, dar,dai);         // - W10*dA
    o6[4] = ar; o6[5] = ai;
}

// dexp^{-1}_{s*k}(w), order 4, Cayley-Hamilton-collapsed (exact):
//   res = w + c1*ad(w) + (c2 + 4*c4*w_k)*ad^2(w).  Safe with &o == &k.
__device__ __forceinline__ void dexpinvP(const M2& k, const M2& w,
                                         float s, M2& o) {
    float u6[6];
    u6[0] = 0.5f*(k.r0.x - k.r1.y); u6[1] = 0.5f*(k.i0.x - k.i1.y);
    u6[2] = k.r0.y; u6[3] = k.i0.y; u6[4] = k.r1.x; u6[5] = k.i1.x;
    float a1[6], a2[6];
    comm_core2(u6, w.r0.y, w.i0.y, w.r1.x, w.i1.x,
               w.r0.x - w.r1.y, w.i0.x - w.i1.y, a1);                  // ad^1
    comm_core2(u6, a1[2],a1[3], a1[4],a1[5], 2.f*a1[0], 2.f*a1[1], a2); // ad^2
    float wkr = fmaf(u6[0],u6[0], -(u6[1]*u6[1]));
    wkr = fmaf(u6[2], u6[4], wkr); wkr = fmaf(-u6[3], u6[5], wkr);
    float wki = 2.f*u6[0]*u6[1];
    wki = fmaf(u6[2], u6[5], wki); wki = fmaf(u6[3], u6[4], wki);
    const float s2  = s*s;
    const float c1  = -0.5f*s;
    const float c2  = s2*(1.f/12.f);
    const float c4m = -(s2*s2)*(1.f/180.f);   // 4*c4
    const float gr = fmaf(c4m, wkr, c2), gi = c4m*wki;
    float acc[6];
#pragma unroll
    for (int p = 0; p < 3; ++p) {
        const float a2r = a2[2*p], a2i = a2[2*p+1];
        acc[2*p]   = fmaf(gr, a2r, fmaf(-gi, a2i, c1*a1[2*p]));
        acc[2*p+1] = fmaf(gr, a2i, fmaf( gi, a2r, c1*a1[2*p+1]));
    }
    // acc[0,1]=00, acc[2,3]=01, acc[4,5]=10; 11 = -00
    o.r0 = w.r0 + mk2(acc[0],  acc[2]);
    o.i0 = w.i0 + mk2(acc[1],  acc[3]);
    o.r1 = w.r1 + mk2(acc[4], -acc[0]);
    o.i1 = w.i1 + mk2(acc[5], -acc[1]);
}

// ---------------- closed-form exp, cosh/sinhc series PAIRED ---------------
// exp(s*k) = e^{c0}(cosh(d) I + sinhc(d) V), w = d^2 complex.
// P = (cosh-acc, sinhc-acc) advances as one packed complex Horner chain.
__device__ __forceinline__ void chstep2(f32x2& Pr, f32x2& Pi,
                                        float wr, float wi, f32x2 K) {
    f32x2 nr = fma2(Pr, sp(wr), fma2(Pi, sp(-wi), K));
    f32x2 ni = fma2(Pr, sp(wi), Pi * sp(wr));
    Pr = nr; Pi = ni;
}
template<bool FULL>
__device__ __forceinline__ void expmP(const M2& k, float s, M2& o) {
    const float hs = 0.5f * s;
    const float c0r = hs*(k.r0.x + k.r1.y), c0i = hs*(k.i0.x + k.i1.y);
    const float v0r = hs*(k.r0.x - k.r1.y), v0i = hs*(k.i0.x - k.i1.y);
    const f32x2 v12r = mk2(s*k.r0.y, s*k.r1.x);   // (v1r, v2r)
    const f32x2 v12i = mk2(s*k.i0.y, s*k.i1.x);   // (v1i, v2i)
    float wr = fmaf(v0r, v0r, -(v0i*v0i));
    wr = fmaf(v12r.x, v12r.y, wr); wr = fmaf(-v12i.x, v12i.y, wr);
    float wi = 2.f*v0r*v0i;
    wi = fmaf(v12r.x, v12i.y, wi); wi = fmaf(v12i.x, v12r.y, wi);
    f32x2 Pr, Pi = sp(0.f);
    if (FULL) {
        Pr = mk2(1.f/40320.f, 1.f/362880.f);
        chstep2(Pr, Pi, wr, wi, mk2(1.f/720.f, 1.f/5040.f));
        chstep2(Pr, Pi, wr, wi, mk2(1.f/24.f,  1.f/120.f));
        chstep2(Pr, Pi, wr, wi, mk2(0.5f,      1.f/6.f));
        chstep2(Pr, Pi, wr, wi, mk2(1.f,       1.f));
    } else {
        Pr = mk2(1.f/24.f, 1.f/120.f);
        chstep2(Pr, Pi, wr, wi, mk2(0.5f, 1.f/6.f));
        chstep2(Pr, Pi, wr, wi, mk2(1.f,  1.f));
    }
    float er, ei;
    if (FULL) {
        const float ex = __expf(c0r);
        er = ex * __cosf(c0i);
        ei = ex * __sinf(c0i);
    } else {
        // e^{c0} = 1 + z(1 + z/2(1 + z/3)), z = c0 (|c0|<~0.05, err ~3e-7)
        float t1r = fmaf(c0r, 1.f/3.f, 1.f), t1i = c0i * (1.f/3.f);
        float t2r, t2i;
        cmul(t2r, t2i, t1r, t1i, c0r, c0i);
        t2r = fmaf(0.5f, t2r, 1.f); t2i *= 0.5f;
        cmul(er, ei, t2r, t2i, c0r, c0i);
        er += 1.f;
    }
    // X = E*(C,S) paired
    f32x2 Xr = fma2(sp(er), Pr, sp(-ei) * Pi);
    f32x2 Xi = fma2(sp(er), Pi, sp( ei) * Pr);
    const float qr = Xr.y, qi = Xi.y;            // q = E*S
    float qv0r, qv0i; cmul(qv0r, qv0i, qr, qi, v0r, v0i);
    // off-diagonals q*(v1,v2) paired
    f32x2 Qr = fma2(sp(qr), v12r, sp(-qi) * v12i);
    f32x2 Qi = fma2(sp(qr), v12i, sp( qi) * v12r);
    o.r0 = mk2(Xr.x + qv0r, Qr.x);
    o.i0 = mk2(Xi.x + qv0i, Qi.x);
    o.r1 = mk2(Qr.y, Xr.x - qv0r);
    o.i1 = mk2(Qi.y, Xi.x - qv0i);
}

// ---------------- LDS access (b128-vectorized, bank-swizzled) ----------------
__device__ __forceinline__ int sbase(int e) { return (e << 3) ^ (e & 4); }

__device__ __forceinline__ M2 lds_loadM(const float* buf, int e) {
    const int b = sbase(e);
    float4 a = *(const float4*)(buf + b);
    float4 c = *(const float4*)(buf + (b ^ 4));
    M2 m;
    m.r0 = mk2(a.x, a.y); m.r1 = mk2(a.z, a.w);
    m.i0 = mk2(c.x, c.y); m.i1 = mk2(c.z, c.w);
    return m;
}
__device__ __forceinline__ void lds_storeM(float* buf, int e, const M2& m) {
    const int b = sbase(e);
    *(float4*)(buf + b)       = make_float4(m.r0.x, m.r0.y, m.r1.x, m.r1.y);
    *(float4*)(buf + (b ^ 4)) = make_float4(m.i0.x, m.i0.y, m.i1.x, m.i1.y);
}

// ---- vector_field: own z0 in regs, neighbors from LDS (packed throughout) ----
__device__ __forceinline__ void vfP(const float* buf, int e,
                                    const M2& z0, M2& o) {
    M2 bc = lds_loadM(buf, e + 1);
    M2 t  = lds_loadM(buf, e + 2);
    bc.r0 = fma2(sp(0.5f), t.r0, bc.r0); bc.r1 = fma2(sp(0.5f), t.r1, bc.r1);
    bc.i0 = fma2(sp(0.5f), t.i0, bc.i0); bc.i1 = fma2(sp(0.5f), t.i1, bc.i1);
    t = lds_loadM(buf, e + 4);
    bc.r0 = fma2(sp(0.25f), t.r0, bc.r0); bc.r1 = fma2(sp(0.25f), t.r1, bc.r1);
    bc.i0 = fma2(sp(0.25f), t.i0, bc.i0); bc.i1 = fma2(sp(0.25f), t.i1, bc.i1);
    t = lds_loadM(buf, e + 8);
    bc.r0 = fma2(sp(0.125f), t.r0, bc.r0); bc.r1 = fma2(sp(0.125f), t.r1, bc.r1);
    bc.i0 = fma2(sp(0.125f), t.i0, bc.i0); bc.i1 = fma2(sp(0.125f), t.i1, bc.i1);
    M2 g = mm2p(z0, bc);
    const float Sr  = z0.r0.y + z0.r1.x, Si  = z0.i0.y + z0.i1.x;  // M01+M10
    const float Ddr = z0.r0.x - z0.r1.y, Ddi = z0.i0.x - z0.i1.y;  // M00-M11
    const float Tr  = z0.r1.x - z0.r0.y, Ti  = z0.i1.x - z0.i0.y;  // M10-M01
    M2 d;
    d.r0 = mk2( 0.5f*Si,        0.5f*(Ddi+Ti));
    d.r1 = mk2( 0.5f*(Ddi-Ti), -0.5f*Si);
    d.i0 = mk2(-0.5f*Sr,       -0.5f*(Ddr+Tr));
    d.i1 = mk2(-0.5f*(Ddr-Tr),  0.5f*Sr);
    o.r0 = fma2(sp(ISCL), g.r0, d.r0);
    o.r1 = fma2(sp(ISCL), g.r1, d.r1);
    o.i0 = fma2(sp(ISCL), g.i0, d.i0);
    o.i1 = fma2(sp(ISCL), g.i1, d.i1);
}

__global__ __launch_bounds__(CC, 3)
void clifford_step_kernel(const float* __restrict__ y, float* __restrict__ out) {
    __shared__ __align__(16) float sy [NY  * SP];  // 9248 B
    __shared__ __align__(16) float szA[NZ  * SP];  // 8992 B (z2, z4)
    __shared__ __align__(16) float szB[NK2 * SP];  // 8736 B (z3)

    const int tid   = threadIdx.x;
    const int row   = blockIdx.x >> 8;      // 65536/256 = 256 chunks per row
    const int chunk = blockIdx.x & 255;
    const int base  = chunk * CC;
    // rotate the halo-heavy wave per block so heavy waves spread across SIMDs
    const int bt    = (tid - ((blockIdx.x & 3) << 6)) & 255;
    const float* __restrict__ yrow = y + (size_t)row * 65536u * 8u;

    // ---- load y tile (+halo) into LDS as planes; own y kept in regs ----
    M2 yreg;
    {
        const int g0 = (base + tid) & 65535;
        const float4* p = (const float4*)(yrow + (size_t)g0 * 8u);
        float4 A = p[0], B = p[1];     // a0..a3 | a4..a7
        yreg.r0 = mk2(A.x + A.w, A.y - B.y);
        yreg.r1 = mk2(A.y + B.y, A.x - A.w);
        yreg.i0 = mk2(B.w + B.x, B.z - A.z);
        yreg.i1 = mk2(B.z + A.z, B.w - B.x);
        lds_storeM(sy, tid, yreg);
        if (bt < NY - CC) {
            const int e  = CC + bt;
            const int g1 = (base + e) & 65535;
            const float4* q = (const float4*)(yrow + (size_t)g1 * 8u);
            float4 Cv = q[0], D = q[1];
            M2 h;
            h.r0 = mk2(Cv.x + Cv.w, Cv.y - D.y);
            h.r1 = mk2(Cv.y + D.y, Cv.x - Cv.w);
            h.i0 = mk2(D.w + D.x, D.z - Cv.z);
            h.i1 = mk2(D.z + Cv.z, D.w - D.x);
            lds_storeM(sy, e, h);
        }
    }
    __syncthreads();                         // bar0

    M2 ka, uacc, zreg, kb;

    // ---- stage 1: k1 = vf(y); z2 = exp(0.05*k1)*y -> szA ----
    vfP(sy, tid, yreg, ka);
    uacc = ka;
    {
        M2 ex; expmP<false>(ka, 0.05f, ex);
        zreg = mm2p(ex, yreg);
        lds_storeM(szA, tid, zreg);
    }
    if (bt < NZ - CC) {
        M2 yv = lds_loadM(sy, CC + bt);
        vfP(sy, CC + bt, yv, kb);
        M2 ex; expmP<false>(kb, 0.05f, ex);
        lds_storeM(szA, CC + bt, mm2p(ex, yv));
    }
    __syncthreads();                         // bar1: RAW on szA

    // ---- stage 2: k2 = dexpinv(0.05*k1, vf(z2)); z3 = exp(0.05*k2)*y -> szB ----
    {
        M2 w; vfP(szA, tid, zreg, w);
        dexpinvP(ka, w, 0.05f, ka);
    }
    uacc.r0 = fma2(sp(2.f), ka.r0, uacc.r0);
    uacc.r1 = fma2(sp(2.f), ka.r1, uacc.r1);
    uacc.i0 = fma2(sp(2.f), ka.i0, uacc.i0);
    uacc.i1 = fma2(sp(2.f), ka.i1, uacc.i1);
    {
        M2 ex; expmP<false>(ka, 0.05f, ex);
        zreg = mm2p(ex, yreg);
        lds_storeM(szB, tid, zreg);
    }
    if (bt < NK2 - CC) {
        M2 z0 = lds_loadM(szA, CC + bt);
        M2 w; vfP(szA, CC + bt, z0, w);
        dexpinvP(kb, w, 0.05f, kb);
        M2 yv = lds_loadM(sy, CC + bt);
        M2 ex; expmP<false>(kb, 0.05f, ex);
        lds_storeM(szB, CC + bt, mm2p(ex, yv));
    }
    __syncthreads();                         // bar2: RAW on szB (+ szA reads done)

    // ---- stage 3: k3 = dexpinv(0.05*k2, vf(z3)); z4 = exp(0.1*k3)*y -> szA ----
    {
        M2 w; vfP(szB, tid, zreg, w);
        dexpinvP(ka, w, 0.05f, ka);
    }
    uacc.r0 = fma2(sp(2.f), ka.r0, uacc.r0);
    uacc.r1 = fma2(sp(2.f), ka.r1, uacc.r1);
    uacc.i0 = fma2(sp(2.f), ka.i0, uacc.i0);
    uacc.i1 = fma2(sp(2.f), ka.i1, uacc.i1);
    {
        M2 ex; expmP<false>(ka, 0.1f, ex);
        zreg = mm2p(ex, yreg);
        lds_storeM(szA, tid, zreg);
    }
    if (bt < NK3 - CC) {
        M2 z0 = lds_loadM(szB, CC + bt);
        M2 w; vfP(szB, CC + bt, z0, w);
        dexpinvP(kb, w, 0.05f, kb);
        M2 yv = lds_loadM(sy, CC + bt);
        M2 ex; expmP<false>(kb, 0.1f, ex);
        lds_storeM(szA, CC + bt, mm2p(ex, yv));
    }
    __syncthreads();                         // bar3: RAW on szA

    // ---- tail: k4, u (sanitized in mv basis), output ----
    {
        M2 w, k4;
        vfP(szA, tid, zreg, w);
        dexpinvP(ka, w, 0.1f, k4);           // ka == k3

        const float s6 = 0.1f / 6.0f;
        M2 um;
        um.r0 = sp(s6) * (uacc.r0 + k4.r0);
        um.r1 = sp(s6) * (uacc.r1 + k4.r1);
        um.i0 = sp(s6) * (uacc.i0 + k4.i0);
        um.i1 = sp(s6) * (uacc.i1 + k4.i1);

        // planes -> mv coeffs, nan_to_num + clip, -> planes
        float av[8];
        av[0] = 0.5f*(um.r0.x + um.r1.y); av[3] = 0.5f*(um.r0.x - um.r1.y);
        av[1] = 0.5f*(um.r0.y + um.r1.x); av[5] = 0.5f*(um.r1.x - um.r0.y);
        av[2] = 0.5f*(um.i1.x - um.i0.y); av[6] = 0.5f*(um.i0.y + um.i1.x);
        av[4] = 0.5f*(um.i0.x - um.i1.y); av[7] = 0.5f*(um.i0.x + um.i1.y);
#pragma unroll
        for (int c = 0; c < 8; ++c) {
            float v = av[c];
            if (isnan(v)) v = 0.f;           // nan_to_num(nan=0); clip handles +-inf
            av[c] = fmaxf(-1.f, fminf(v, 1.f));
        }
        um.r0 = mk2(av[0] + av[3], av[1] - av[5]);
        um.r1 = mk2(av[1] + av[5], av[0] - av[3]);
        um.i0 = mk2(av[7] + av[4], av[6] - av[2]);
        um.i1 = mk2(av[6] + av[2], av[7] - av[4]);

        M2 ex; expmP<true>(um, 1.f, ex);
        M2 om = mm2p(ex, yreg);

        float* dst = out + ((size_t)row * 65536u + (size_t)(base + tid)) * 8u;
        ((float4*)dst)[0] = make_float4(0.5f*(om.r0.x + om.r1.y),
                                        0.5f*(om.r0.y + om.r1.x),
                                        0.5f*(om.i1.x - om.i0.y),
                                        0.5f*(om.r0.x - om.r1.y));
        ((float4*)dst)[1] = make_float4(0.5f*(om.i0.x - om.i1.y),
                                        0.5f*(om.r1.x - om.r0.y),
                                        0.5f*(om.i0.y + om.i1.x),
                                        0.5f*(om.i0.x + om.i1.y));
    }
}

extern "C" void kernel_launch(void* const* d_in, const int* in_sizes, int n_in,
                              void* d_out, int out_size, void* d_ws, size_t ws_size,
                              hipStream_t stream) {
    const float* y = (const float*)d_in[0];
    float* out = (float*)d_out;
    dim3 grid(32 * 256);   // 32 rows x 256 chunks of 256 elements
    dim3 block(CC);
    hipLaunchKernelGGL(clifford_step_kernel, grid, block, 0, stream, y, out);
}